// Round 1
// baseline (1389.823 us; speedup 1.0000x reference)
//
#include <hip/hip_runtime.h>
#include <hip/hip_bf16.h>
#include <math.h>

#define NUM_SEG 131072

// Kernel 1: logits[i] = dot(X[i,:], W) + b.
// Each wave handles 4 rows per iteration: lane l -> row (l>>4), float4 col (l&15).
// One global_load_dwordx4 per lane covers 1024 contiguous bytes per wave instr
// (perfect coalescing); 4-step shfl_xor butterfly reduces within 16-lane groups.
__global__ __launch_bounds__(256) void clr_logits(const float* __restrict__ X,
                                                  const float* __restrict__ W,
                                                  const float* __restrict__ b,
                                                  float* __restrict__ logits,
                                                  int N) {
    const int lane = threadIdx.x & 63;
    const int sub  = lane >> 4;   // row within 4-row group
    const int c4   = lane & 15;   // float4 column index (D=64 -> 16 float4s)
    const float4* __restrict__ W4 = reinterpret_cast<const float4*>(W);
    const float4  w4   = W4[c4];
    const float   bias = b[0];
    const float4* __restrict__ X4 = reinterpret_cast<const float4*>(X);

    const int wave   = (int)((blockIdx.x * blockDim.x + threadIdx.x) >> 6);
    const int nwaves = (int)((gridDim.x * blockDim.x) >> 6);

    for (int base = wave * 4; base < N; base += nwaves * 4) {
        const int row = base + sub;
        float p = 0.0f;
        if (row < N) {
            const float4 x4 = X4[row * 16 + c4];
            p = x4.x * w4.x + x4.y * w4.y + x4.z * w4.z + x4.w * w4.w;
        }
        // butterfly sum across the 16 lanes sharing one row
        p += __shfl_xor(p, 1);
        p += __shfl_xor(p, 2);
        p += __shfl_xor(p, 4);
        p += __shfl_xor(p, 8);
        if (c4 == 0 && row < N) logits[row] = p + bias;
    }
}

// Kernel 2: segment boundaries from the sorted id array. Exactly one writer
// per slot -> no atomics. Empty segments keep start=end=0 (memset) -> skipped.
__global__ __launch_bounds__(256) void clr_bounds(const int* __restrict__ seg,
                                                  int* __restrict__ sstart,
                                                  int* __restrict__ send,
                                                  int N) {
    const int i = blockIdx.x * blockDim.x + threadIdx.x;
    if (i >= N) return;
    const int s = seg[i];
    if (i == 0) {
        sstart[s] = 0;
    } else {
        const int p = seg[i - 1];
        if (p != s) {
            sstart[s] = i;
            send[p]   = i;
        }
    }
    if (i == N - 1) send[s] = N;
}

// Kernel 3: one wave per segment. Avg segment length ~32 (< 64), so the loops
// are almost always single-trip. Segment rows are contiguous & L1-hot, so the
// second exp() read costs nothing at HBM level.
__global__ __launch_bounds__(256) void clr_softmax(const float* __restrict__ logits,
                                                   const int* __restrict__ sstart,
                                                   const int* __restrict__ send,
                                                   float* __restrict__ out,
                                                   int numseg) {
    const int wave = (int)((blockIdx.x * blockDim.x + threadIdx.x) >> 6);
    const int lane = threadIdx.x & 63;
    if (wave >= numseg) return;
    const int s = sstart[wave];
    const int e = send[wave];
    if (e <= s) return;  // empty segment

    float m = -INFINITY;
    for (int i = s + lane; i < e; i += 64) m = fmaxf(m, logits[i]);
    #pragma unroll
    for (int k = 1; k < 64; k <<= 1) m = fmaxf(m, __shfl_xor(m, k));

    float sum = 0.0f;
    for (int i = s + lane; i < e; i += 64) sum += __expf(logits[i] - m);
    #pragma unroll
    for (int k = 1; k < 64; k <<= 1) sum += __shfl_xor(sum, k);

    const float inv = 1.0f / sum;
    for (int i = s + lane; i < e; i += 64) out[i] = __expf(logits[i] - m) * inv;
}

extern "C" void kernel_launch(void* const* d_in, const int* in_sizes, int n_in,
                              void* d_out, int out_size, void* d_ws, size_t ws_size,
                              hipStream_t stream) {
    const float* X   = (const float*)d_in[0];
    const int*   seg = (const int*)d_in[1];
    const float* W   = (const float*)d_in[2];
    const float* b   = (const float*)d_in[3];
    const int N = in_sizes[1];          // segment_ids element count == row count
    float* out = (float*)d_out;

    // workspace layout: [ logits: N floats ][ sstart: NUM_SEG ints ][ send: NUM_SEG ints ]
    float* logits = (float*)d_ws;
    int*   sstart = (int*)((char*)d_ws + (size_t)N * sizeof(float));
    int*   send   = sstart + NUM_SEG;

    hipMemsetAsync(sstart, 0, 2 * (size_t)NUM_SEG * sizeof(int), stream);

    clr_logits<<<4096, 256, 0, stream>>>(X, W, b, logits, N);
    clr_bounds<<<(N + 255) / 256, 256, 0, stream>>>(seg, sstart, send, N);
    clr_softmax<<<(NUM_SEG + 3) / 4, 256, 0, stream>>>(logits, sstart, send, out, NUM_SEG);
}